// Round 1
// baseline (75.032 us; speedup 1.0000x reference)
//
#include <hip/hip_runtime.h>

// MHAGRU: input_proj -> per-feature GRU (scan over T) -> shared MHA over time -> out_proj
// B=32 T=64 F=128 H=8 NH=4 HD=2 HID=32. All f32.
// d_out = [ y (B*T*HID) | attention (B*T*F*H) ]
// d_ws  = [ xp (B*T*F) | out (B*F*T*H) ]   (~9.4 MB)

namespace {
constexpr int Bb = 32, Tt = 64, Ff = 128, Hh = 8, NHh = 4, HIDh = 32;
constexpr int G3H = 24;  // 3*H
}

__device__ __forceinline__ float sigmoidf_(float x) { return 1.0f / (1.0f + __expf(-x)); }
__device__ __forceinline__ float tanhf_(float x) { return 1.0f - 2.0f / (__expf(2.0f * x) + 1.0f); }

// ---------------- K1: xp[b,t,f] = x[b,t,:] . Wp[f,:] + bp[f] ----------------
// grid: B*(T/8) = 256 blocks, 128 threads (thread = f), 8 t per block.
__global__ __launch_bounds__(128) void k_input_proj(
    const float* __restrict__ x, const float* __restrict__ Wp,
    const float* __restrict__ bp, float* __restrict__ xp) {
  constexpr int TT = 8;
  int blk = blockIdx.x;
  int b = blk >> 3;
  int t0 = (blk & 7) * TT;
  int f = threadIdx.x;
  __shared__ float xs[TT][Ff];
  const float* xb = x + (b * Tt + t0) * Ff;
  for (int i = threadIdx.x; i < TT * Ff; i += 128) xs[i >> 7][i & 127] = xb[i];
  __syncthreads();
  float acc[TT];
  float bf = bp[f];
#pragma unroll
  for (int tt = 0; tt < TT; ++tt) acc[tt] = bf;
  const float4* wr = (const float4*)(Wp + f * Ff);
#pragma unroll 4
  for (int k4 = 0; k4 < Ff / 4; ++k4) {
    float4 w = wr[k4];
#pragma unroll
    for (int tt = 0; tt < TT; ++tt) {
      float s = acc[tt];
      s = fmaf(xs[tt][4 * k4 + 0], w.x, s);
      s = fmaf(xs[tt][4 * k4 + 1], w.y, s);
      s = fmaf(xs[tt][4 * k4 + 2], w.z, s);
      s = fmaf(xs[tt][4 * k4 + 3], w.w, s);
      acc[tt] = s;
    }
  }
  float* xpb = xp + (b * Tt + t0) * Ff + f;
#pragma unroll
  for (int tt = 0; tt < TT; ++tt) xpb[tt * Ff] = acc[tt];
}

// ---------------- K2: per-feature GRU scan over T ----------------
// grid: B*(F/8) = 512 blocks, 64 threads = 8 groups(f) x 8 lanes(j=hidden idx).
// W_hh rows (j, 8+j, 16+j) live in registers; h vector replicated per lane,
// redistributed via 8 shuffles per step (group is within one wave -> no barrier).
__global__ __launch_bounds__(64) void k_gru(
    const float* __restrict__ xp, const float* __restrict__ W_ih,
    const float* __restrict__ b_ih, const float* __restrict__ W_hh,
    const float* __restrict__ b_hh, float* __restrict__ outp) {
  int blk = blockIdx.x;
  int b = blk >> 4;
  int f0 = (blk & 15) * 8;
  int tid = threadIdx.x;
  int g = tid >> 3, j = tid & 7;
  int f = f0 + g;
  __shared__ float xs[Tt][8];
  const float* xpb = xp + b * Tt * Ff + f0;
  for (int i = tid; i < Tt * 8; i += 64) xs[i >> 3][i & 7] = xpb[(i >> 3) * Ff + (i & 7)];
  const float* wb = W_hh + (f * G3H + j) * Hh;  // row j of W_hh[f]
  float w0[8], w1[8], w2[8];
#pragma unroll
  for (int h = 0; h < 8; ++h) {
    w0[h] = wb[h];        // gate r row j
    w1[h] = wb[64 + h];   // gate z row 8+j
    w2[h] = wb[128 + h];  // gate n row 16+j
  }
  float wi0 = W_ih[f * G3H + j], wi1 = W_ih[f * G3H + 8 + j], wi2 = W_ih[f * G3H + 16 + j];
  float bi0 = b_ih[f * G3H + j], bi1 = b_ih[f * G3H + 8 + j], bi2 = b_ih[f * G3H + 16 + j];
  float bh0 = b_hh[f * G3H + j], bh1 = b_hh[f * G3H + 8 + j], bh2 = b_hh[f * G3H + 16 + j];
  float hall[8];
#pragma unroll
  for (int h = 0; h < 8; ++h) hall[h] = 0.f;
  __syncthreads();
  float* outb = outp + (b * Ff + f) * Tt * Hh + j;
  int base = tid & 56;
  for (int t = 0; t < Tt; ++t) {
    float xt = xs[t][g];
    float a0 = bh0, a1 = bh1, a2 = bh2;
#pragma unroll
    for (int h = 0; h < 8; ++h) {
      a0 = fmaf(hall[h], w0[h], a0);
      a1 = fmaf(hall[h], w1[h], a1);
      a2 = fmaf(hall[h], w2[h], a2);
    }
    float r = sigmoidf_(fmaf(xt, wi0, bi0) + a0);
    float z = sigmoidf_(fmaf(xt, wi1, bi1) + a1);
    float n = tanhf_(fmaf(r, a2, fmaf(xt, wi2, bi2)));
    float hn = fmaf(z, hall[j] - n, n);  // (1-z)*n + z*h
    outb[t * Hh] = hn;
#pragma unroll
    for (int h = 0; h < 8; ++h) hall[h] = __shfl(hn, base + h, 64);
  }
}

// ---------------- K3: MHA over time per (b,f) ----------------
// grid: B*F = 4096 blocks, 64 threads (lane = time row t).
// k,v staged transposed [8][64] in LDS (conflict-free); softmax without
// max-subtraction (scores are O(1) by construction) -> single fused pass.
__global__ __launch_bounds__(64) void k_mha(
    const float* __restrict__ outp, const float* __restrict__ in_w,
    const float* __restrict__ in_b, const float* __restrict__ ow,
    const float* __restrict__ ob, float* __restrict__ attn) {
  int blk = blockIdx.x;  // b*F + f
  int t = threadIdx.x;
  __shared__ float kk[Hh][Tt];
  __shared__ float vv[Hh][Tt];
  const float4* src = (const float4*)(outp + blk * (Tt * Hh));
  float4 r0 = src[t * 2], r1 = src[t * 2 + 1];
  float sq[8] = {r0.x, r0.y, r0.z, r0.w, r1.x, r1.y, r1.z, r1.w};
  float q[8];
#pragma unroll
  for (int jj = 0; jj < 8; ++jj) {
    float aq = in_b[jj], ak = in_b[8 + jj], av = in_b[16 + jj];
#pragma unroll
    for (int h = 0; h < 8; ++h) {
      aq = fmaf(sq[h], in_w[jj * 8 + h], aq);
      ak = fmaf(sq[h], in_w[(8 + jj) * 8 + h], ak);
      av = fmaf(sq[h], in_w[(16 + jj) * 8 + h], av);
    }
    q[jj] = aq;
    kk[jj][t] = ak;
    vv[jj][t] = av;
  }
  __syncthreads();
  constexpr float scale = 0.70710678118654752440f;  // 1/sqrt(HD=2)
  float ctx[8];
#pragma unroll
  for (int n = 0; n < NHh; ++n) {
    float q0 = q[2 * n] * scale, q1 = q[2 * n + 1] * scale;
    float psum = 0.f, c0 = 0.f, c1 = 0.f;
    for (int kt = 0; kt < Tt; ++kt) {
      float s = fmaf(q0, kk[2 * n][kt], q1 * kk[2 * n + 1][kt]);
      float p = __expf(s);
      psum += p;
      c0 = fmaf(p, vv[2 * n][kt], c0);
      c1 = fmaf(p, vv[2 * n + 1][kt], c1);
    }
    float inv = 1.f / psum;
    ctx[2 * n] = c0 * inv;
    ctx[2 * n + 1] = c1 * inv;
  }
  int b = blk >> 7, f = blk & 127;
  float* dst = attn + ((b * Tt + t) * Ff + f) * Hh;
  float out8[8];
#pragma unroll
  for (int jj = 0; jj < 8; ++jj) {
    float a = ob[jj];
#pragma unroll
    for (int h = 0; h < 8; ++h) a = fmaf(ctx[h], ow[jj * 8 + h], a);
    out8[jj] = a;
  }
  float4 o0 = {out8[0], out8[1], out8[2], out8[3]};
  float4 o1 = {out8[4], out8[5], out8[6], out8[7]};
  ((float4*)dst)[0] = o0;
  ((float4*)dst)[1] = o1;
}

// ---------------- K4: y[b,t,o] = out[b,t,:,:] . Wout[o,:] + bout[o] ----------------
// grid: B*(T/8) = 256 blocks, 128 threads = 8 o-quads x 16 f-chunks.
// Register tile [8tt x 4o], global reads (ws is L2-hot), shfl_xor reduction.
__global__ __launch_bounds__(128) void k_outproj(
    const float* __restrict__ outp, const float* __restrict__ Wout,
    const float* __restrict__ bout, float* __restrict__ y) {
  constexpr int TT = 8;
  int blk = blockIdx.x;
  int b = blk >> 3;
  int t0 = (blk & 7) * TT;
  int tid = threadIdx.x;
  int oq = tid >> 4;  // 0..7 -> o in [oq*4, oq*4+4)
  int fc = tid & 15;  // 0..15 -> f in [fc*8, fc*8+8)
  float acc[TT][4];
#pragma unroll
  for (int tt = 0; tt < TT; ++tt)
#pragma unroll
    for (int od = 0; od < 4; ++od) acc[tt][od] = 0.f;
#pragma unroll
  for (int ff = 0; ff < 8; ++ff) {
    int f = fc * 8 + ff;
    const float4* rb = (const float4*)(outp + ((b * Ff + f) * Tt + t0) * Hh);
    float4 rv[16];  // [tt][h/4] : 8 t x 8 h contiguous
#pragma unroll
    for (int i = 0; i < 16; ++i) rv[i] = rb[i];
#pragma unroll
    for (int od = 0; od < 4; ++od) {
      int o = oq * 4 + od;
      const float4* wbp = (const float4*)(Wout + o * (Ff * Hh) + f * Hh);
      float4 wa = wbp[0], wc = wbp[1];
#pragma unroll
      for (int tt = 0; tt < TT; ++tt) {
        float4 ra = rv[tt * 2], rc = rv[tt * 2 + 1];
        float s = acc[tt][od];
        s = fmaf(ra.x, wa.x, s);
        s = fmaf(ra.y, wa.y, s);
        s = fmaf(ra.z, wa.z, s);
        s = fmaf(ra.w, wa.w, s);
        s = fmaf(rc.x, wc.x, s);
        s = fmaf(rc.y, wc.y, s);
        s = fmaf(rc.z, wc.z, s);
        s = fmaf(rc.w, wc.w, s);
        acc[tt][od] = s;
      }
    }
  }
  // reduce over the 16 f-chunk lanes (within-wave butterfly)
#pragma unroll
  for (int tt = 0; tt < TT; ++tt)
#pragma unroll
    for (int od = 0; od < 4; ++od) {
      float v = acc[tt][od];
      v += __shfl_xor(v, 1, 16);
      v += __shfl_xor(v, 2, 16);
      v += __shfl_xor(v, 4, 16);
      v += __shfl_xor(v, 8, 16);
      acc[tt][od] = v;
    }
#pragma unroll
  for (int tt = 0; tt < TT; ++tt) {
    if (fc == tt) {  // static register indexing; predicated write
#pragma unroll
      for (int od = 0; od < 4; ++od) {
        int o = oq * 4 + od;
        y[(b * Tt + t0 + tt) * HIDh + o] = acc[tt][od] + bout[o];
      }
    }
  }
}

extern "C" void kernel_launch(void* const* d_in, const int* in_sizes, int n_in,
                              void* d_out, int out_size, void* d_ws, size_t ws_size,
                              hipStream_t stream) {
  (void)in_sizes; (void)n_in; (void)out_size; (void)ws_size;
  const float* x    = (const float*)d_in[0];
  const float* Wp   = (const float*)d_in[1];
  const float* bp   = (const float*)d_in[2];
  const float* W_ih = (const float*)d_in[3];
  const float* b_ih = (const float*)d_in[4];
  const float* W_hh = (const float*)d_in[5];
  const float* b_hh = (const float*)d_in[6];
  const float* in_w = (const float*)d_in[7];
  const float* in_b = (const float*)d_in[8];
  const float* ow   = (const float*)d_in[9];
  const float* ob   = (const float*)d_in[10];
  const float* Wout = (const float*)d_in[11];
  const float* bout = (const float*)d_in[12];

  float* y    = (float*)d_out;                       // B*T*HID
  float* attn = (float*)d_out + Bb * Tt * HIDh;      // B*T*F*H
  float* xp   = (float*)d_ws;                        // B*T*F
  float* outp = (float*)d_ws + Bb * Tt * Ff;         // B*F*T*H

  hipLaunchKernelGGL(k_input_proj, dim3(Bb * (Tt / 8)), dim3(128), 0, stream, x, Wp, bp, xp);
  hipLaunchKernelGGL(k_gru, dim3(Bb * (Ff / 8)), dim3(64), 0, stream, xp, W_ih, b_ih, W_hh, b_hh, outp);
  hipLaunchKernelGGL(k_mha, dim3(Bb * Ff), dim3(64), 0, stream, outp, in_w, in_b, ow, ob, attn);
  hipLaunchKernelGGL(k_outproj, dim3(Bb * (Tt / 8)), dim3(128), 0, stream, outp, Wout, bout, y);
}

// Round 2
// 72.783 us; speedup vs baseline: 1.0309x; 1.0309x over previous
//
#include <hip/hip_runtime.h>

// MHAGRU fused: [input_proj + per-feature GRU + shared MHA] in one kernel, + out_proj.
// B=32 T=64 F=128 H=8 NH=4 HD=2 HID=32. All f32.
// d_out = [ y (B*T*HID) | attention (B*T*F*H) ]
// d_ws  = [ out (B*F*T*H) ]  (8 MB, fully overwritten each call)

namespace {
constexpr int Bb = 32, Tt = 64, Ff = 128, Hh = 8, HIDh = 32;
constexpr int G3H = 24;  // 3*H
// fused-kernel LDS layout (floats):
constexpr int XS_STRIDE = 130;            // x tile row stride (float2-aligned, 2-way banks)
constexpr int XS_FLOATS = Tt * XS_STRIDE; // 8320 (phase A only)
constexpr int HOUT_OFF = 0;               // hout[fl*520 + j*65 + t] : 4160 floats (B->C)
constexpr int KVS_OFF  = 4160;            // kv[wave*1024 + t*16 + n*4] : 4096 floats (C)
constexpr int XP_OFF   = 8320;            // xp_s[g*65 + t] : 520 floats (A->B)
constexpr int SMEM_FLOATS = 8840;         // 35.4 KB -> 2 blocks/CU
}

__device__ __forceinline__ float sigmoidf_(float x) { return 1.0f / (1.0f + __expf(-x)); }
__device__ __forceinline__ float tanhf_(float x) { return 1.0f - 2.0f / (__expf(2.0f * x) + 1.0f); }
__device__ __forceinline__ float fexp2_(float x) {
#if __has_builtin(__builtin_amdgcn_exp2f)
  return __builtin_amdgcn_exp2f(x);   // v_exp_f32: D = 2^x
#else
  return __expf(x * 0.69314718055994531f);
#endif
}

// ---------------- fused: input_proj -> GRU scan -> MHA ----------------
// grid: B * (F/8) = 512 blocks, 256 threads = 4 waves.
__global__ __launch_bounds__(256) void k_fused(
    const float* __restrict__ x, const float* __restrict__ Wp, const float* __restrict__ bp,
    const float* __restrict__ W_ih, const float* __restrict__ b_ih,
    const float* __restrict__ W_hh, const float* __restrict__ b_hh,
    const float* __restrict__ in_w, const float* __restrict__ in_b,
    const float* __restrict__ ow, const float* __restrict__ ob,
    float* __restrict__ outp, float* __restrict__ attn) {
  __shared__ float smem[SMEM_FLOATS];
  const int tid = threadIdx.x;
  const int blk = blockIdx.x;
  const int b = blk >> 4;
  const int f0 = (blk & 15) * 8;
  const int lane = tid & 63;
  const int w = tid >> 6;

  // ---- phase A: stage x[b] (64x128) into LDS; compute xp for this block's 8 f's ----
  {
    const float2* xb = (const float2*)(x + b * Tt * Ff);
    for (int i = tid; i < Tt * Ff / 2; i += 256) {
      int row = i >> 6, col2 = i & 63;
      *(float2*)&smem[row * XS_STRIDE + col2 * 2] = xb[i];
    }
  }
  __syncthreads();
  {
    const int t = lane;
    const int fA = f0 + w, fB = f0 + w + 4;      // wave-uniform -> Wp rows are scalar loads
    float acc0 = bp[fA], acc1 = bp[fB];
    const float* wA = Wp + fA * Ff;
    const float* wB = Wp + fB * Ff;
    const float* xr = &smem[t * XS_STRIDE];
#pragma unroll 8
    for (int k = 0; k < Ff; k += 2) {
      float2 xv = *(const float2*)&xr[k];
      acc0 = fmaf(xv.x, wA[k], acc0); acc0 = fmaf(xv.y, wA[k + 1], acc0);
      acc1 = fmaf(xv.x, wB[k], acc1); acc1 = fmaf(xv.y, wB[k + 1], acc1);
    }
    smem[XP_OFF + w * 65 + t] = acc0;            // xp_s[g=w][t]
    smem[XP_OFF + (w + 4) * 65 + t] = acc1;      // xp_s[g=w+4][t]
  }
  __syncthreads();   // xp_s ready; all reads of x-tile done (region reused below)

  // ---- phase B: GRU scan over T, wave 0 only. lane = (g=f_local, j=hidden idx) ----
  if (tid < 64) {
    const int g = tid >> 3, j = tid & 7;
    const int f = f0 + g;
    const float* wb = W_hh + (f * G3H + j) * Hh;
    float w0[8], w1[8], w2[8];
#pragma unroll
    for (int h = 0; h < 8; ++h) { w0[h] = wb[h]; w1[h] = wb[64 + h]; w2[h] = wb[128 + h]; }
    const float wi0 = W_ih[f * G3H + j], wi1 = W_ih[f * G3H + 8 + j], wi2 = W_ih[f * G3H + 16 + j];
    const float bi0 = b_ih[f * G3H + j], bi1 = b_ih[f * G3H + 8 + j], bi2 = b_ih[f * G3H + 16 + j];
    const float bh0 = b_hh[f * G3H + j], bh1 = b_hh[f * G3H + 8 + j], bh2 = b_hh[f * G3H + 16 + j];
    float hall[8];
#pragma unroll
    for (int h = 0; h < 8; ++h) hall[h] = 0.f;
    const int base = tid & 56;
    float* hdst = &smem[HOUT_OFF + g * 520 + j * 65];  // banks (tid+t)%32: 2-way = free
    const float* xps = &smem[XP_OFF + g * 65];         // broadcast within j-group
    for (int t = 0; t < Tt; ++t) {
      float xt = xps[t];
      float a0 = bh0, a1 = bh1, a2 = bh2;
#pragma unroll
      for (int h = 0; h < 8; ++h) {
        a0 = fmaf(hall[h], w0[h], a0);
        a1 = fmaf(hall[h], w1[h], a1);
        a2 = fmaf(hall[h], w2[h], a2);
      }
      float r = sigmoidf_(fmaf(xt, wi0, bi0) + a0);
      float z = sigmoidf_(fmaf(xt, wi1, bi1) + a1);
      float n = tanhf_(fmaf(r, a2, fmaf(xt, wi2, bi2)));
      float hn = fmaf(z, hall[j] - n, n);   // (1-z)*n + z*h
      hdst[t] = hn;
#pragma unroll
      for (int h = 0; h < 8; ++h) hall[h] = __shfl(hn, base + h, 64);
    }
  }
  __syncthreads();   // hout ready for all waves

  // ---- phase C: MHA per f; wave w handles f_local = w and w+4. lane = t ----
  {
    const int t = lane;
    float* kvw = &smem[KVS_OFF + w * 1024];
    for (int fl = w; fl < 8; fl += 4) {
      const int f = f0 + fl;
      const float* hsrc = &smem[HOUT_OFF + fl * 520];
      float sq[8];
#pragma unroll
      for (int h = 0; h < 8; ++h) sq[h] = hsrc[h * 65 + t];   // conflict-free
      // coalesced h -> global ws for out_proj kernel
      {
        float4* og = (float4*)(outp + ((b * Ff + f) * Tt + t) * Hh);
        float4 h0 = {sq[0], sq[1], sq[2], sq[3]};
        float4 h1 = {sq[4], sq[5], sq[6], sq[7]};
        og[0] = h0; og[1] = h1;
      }
      // qkv projection (in_w wave-uniform -> scalar loads)
      float q[8], ka[8], va[8];
#pragma unroll
      for (int jj = 0; jj < 8; ++jj) {
        float aq = in_b[jj], ak = in_b[8 + jj], av = in_b[16 + jj];
#pragma unroll
        for (int h = 0; h < 8; ++h) {
          aq = fmaf(sq[h], in_w[jj * 8 + h], aq);
          ak = fmaf(sq[h], in_w[(8 + jj) * 8 + h], ak);
          av = fmaf(sq[h], in_w[(16 + jj) * 8 + h], av);
        }
        q[jj] = aq; ka[jj] = ak; va[jj] = av;
      }
      // pack per-head (k0,k1,v0,v1) for uniform-broadcast b128 reads
#pragma unroll
      for (int n = 0; n < 4; ++n) {
        float4 kv = {ka[2 * n], ka[2 * n + 1], va[2 * n], va[2 * n + 1]};
        *(float4*)&kvw[t * 16 + n * 4] = kv;
      }
      asm volatile("s_waitcnt lgkmcnt(0)" ::: "memory");  // within-wave cross-lane LDS RAW
      // online (un-maxed) softmax + PV; p = 2^(q.k * scale * log2e) exactly equals exp(q.k*scale)
      constexpr float SCL = 0.70710678118654752f * 1.44269504088896341f;
      float ctx[8];
#pragma unroll
      for (int n = 0; n < 4; ++n) {
        float qs0 = q[2 * n] * SCL, qs1 = q[2 * n + 1] * SCL;
        float psum = 0.f, c0 = 0.f, c1 = 0.f;
        for (int kt = 0; kt < Tt; ++kt) {
          float4 kv = *(const float4*)&kvw[kt * 16 + n * 4];  // uniform addr -> broadcast
          float s = fmaf(qs0, kv.x, qs1 * kv.y);
          float p = fexp2_(s);
          psum += p;
          c0 = fmaf(p, kv.z, c0);
          c1 = fmaf(p, kv.w, c1);
        }
        float inv = 1.f / psum;
        ctx[2 * n] = c0 * inv;
        ctx[2 * n + 1] = c1 * inv;
      }
      // out_proj of attention + store
      float o8[8];
#pragma unroll
      for (int jj = 0; jj < 8; ++jj) {
        float a = ob[jj];
#pragma unroll
        for (int h = 0; h < 8; ++h) a = fmaf(ctx[h], ow[jj * 8 + h], a);
        o8[jj] = a;
      }
      float4* dst = (float4*)(attn + ((b * Tt + t) * Ff + f) * Hh);
      float4 o0 = {o8[0], o8[1], o8[2], o8[3]};
      float4 o1 = {o8[4], o8[5], o8[6], o8[7]};
      dst[0] = o0; dst[1] = o1;
    }
  }
}

// ---------------- K4: y[b,t,o] = out[b,t,:,:] . Wout[o,:] + bout[o] ----------------
// grid: B*(T/8) = 256 blocks, 128 threads = 8 o-quads x 16 f-chunks.
__global__ __launch_bounds__(128) void k_outproj(
    const float* __restrict__ outp, const float* __restrict__ Wout,
    const float* __restrict__ bout, float* __restrict__ y) {
  constexpr int TT = 8;
  int blk = blockIdx.x;
  int b = blk >> 3;
  int t0 = (blk & 7) * TT;
  int tid = threadIdx.x;
  int oq = tid >> 4;  // o in [oq*4, oq*4+4)
  int fc = tid & 15;  // f in [fc*8, fc*8+8)
  float acc[TT][4];
#pragma unroll
  for (int tt = 0; tt < TT; ++tt)
#pragma unroll
    for (int od = 0; od < 4; ++od) acc[tt][od] = 0.f;
#pragma unroll
  for (int ff = 0; ff < 8; ++ff) {
    int f = fc * 8 + ff;
    const float4* rb = (const float4*)(outp + ((b * Ff + f) * Tt + t0) * Hh);
    float4 rv[16];
#pragma unroll
    for (int i = 0; i < 16; ++i) rv[i] = rb[i];
#pragma unroll
    for (int od = 0; od < 4; ++od) {
      int o = oq * 4 + od;
      const float4* wbp = (const float4*)(Wout + o * (Ff * Hh) + f * Hh);
      float4 wa = wbp[0], wc = wbp[1];
#pragma unroll
      for (int tt = 0; tt < TT; ++tt) {
        float4 ra = rv[tt * 2], rc = rv[tt * 2 + 1];
        float s = acc[tt][od];
        s = fmaf(ra.x, wa.x, s); s = fmaf(ra.y, wa.y, s);
        s = fmaf(ra.z, wa.z, s); s = fmaf(ra.w, wa.w, s);
        s = fmaf(rc.x, wc.x, s); s = fmaf(rc.y, wc.y, s);
        s = fmaf(rc.z, wc.z, s); s = fmaf(rc.w, wc.w, s);
        acc[tt][od] = s;
      }
    }
  }
#pragma unroll
  for (int tt = 0; tt < TT; ++tt)
#pragma unroll
    for (int od = 0; od < 4; ++od) {
      float v = acc[tt][od];
      v += __shfl_xor(v, 1, 16);
      v += __shfl_xor(v, 2, 16);
      v += __shfl_xor(v, 4, 16);
      v += __shfl_xor(v, 8, 16);
      acc[tt][od] = v;
    }
#pragma unroll
  for (int tt = 0; tt < TT; ++tt) {
    if (fc == tt) {
#pragma unroll
      for (int od = 0; od < 4; ++od) {
        int o = oq * 4 + od;
        y[(b * Tt + t0 + tt) * HIDh + o] = acc[tt][od] + bout[o];
      }
    }
  }
}

extern "C" void kernel_launch(void* const* d_in, const int* in_sizes, int n_in,
                              void* d_out, int out_size, void* d_ws, size_t ws_size,
                              hipStream_t stream) {
  (void)in_sizes; (void)n_in; (void)out_size; (void)ws_size;
  const float* x    = (const float*)d_in[0];
  const float* Wp   = (const float*)d_in[1];
  const float* bp   = (const float*)d_in[2];
  const float* W_ih = (const float*)d_in[3];
  const float* b_ih = (const float*)d_in[4];
  const float* W_hh = (const float*)d_in[5];
  const float* b_hh = (const float*)d_in[6];
  const float* in_w = (const float*)d_in[7];
  const float* in_b = (const float*)d_in[8];
  const float* ow   = (const float*)d_in[9];
  const float* ob   = (const float*)d_in[10];
  const float* Wout = (const float*)d_in[11];
  const float* bout = (const float*)d_in[12];

  float* y    = (float*)d_out;                   // B*T*HID
  float* attn = (float*)d_out + Bb * Tt * HIDh;  // B*T*F*H
  float* outp = (float*)d_ws;                    // B*F*T*H

  hipLaunchKernelGGL(k_fused, dim3(Bb * (Ff / 8)), dim3(256), 0, stream,
                     x, Wp, bp, W_ih, b_ih, W_hh, b_hh, in_w, in_b, ow, ob, outp, attn);
  hipLaunchKernelGGL(k_outproj, dim3(Bb * (Tt / 8)), dim3(128), 0, stream,
                     outp, Wout, bout, y);
}

// Round 3
// 70.760 us; speedup vs baseline: 1.0604x; 1.0286x over previous
//
#include <hip/hip_runtime.h>

// MHAGRU fused: [input_proj + per-feature GRU + shared MHA] in one kernel, + out_proj.
// B=32 T=64 F=128 H=8 NH=4 HD=2 HID=32. All f32.
// d_out = [ y (B*T*HID) | attention (B*T*F*H) ]
// d_ws  = [ out (B*F*T*H) ]  (8 MB, fully overwritten each call)
//
// R2 change: all sigmoid/tanh/softmax divisions -> v_rcp_f32; all exp -> v_exp_f32
// (exp2 with log2e pre-folded into GRU weights). IEEE fdiv was ~12 instr + ~50cyc
// latency, 3x in the serial GRU chain.

namespace {
constexpr int Bb = 32, Tt = 64, Ff = 128, Hh = 8, HIDh = 32;
constexpr int G3H = 24;  // 3*H
// fused-kernel LDS layout (floats):
constexpr int XS_STRIDE = 130;            // x tile row stride
constexpr int HOUT_OFF = 0;               // hout[fl*520 + j*65 + t] : 4160 floats (B->C)
constexpr int KVS_OFF  = 4160;            // kv[wave*1024 + t*16 + n*4] : 4096 floats (C)
constexpr int XP_OFF   = 8320;            // xp_s[g*65 + t] : 520 floats (A->B)
constexpr int SMEM_FLOATS = 8840;         // 35.4 KB -> 2 blocks/CU
constexpr float L2E = 1.44269504088896340736f;
}

__device__ __forceinline__ float rcp_(float x) {
#if __has_builtin(__builtin_amdgcn_rcpf)
  return __builtin_amdgcn_rcpf(x);   // v_rcp_f32, ~1ulp
#else
  return 1.0f / x;
#endif
}
__device__ __forceinline__ float exp2_(float x) {
#if __has_builtin(__builtin_amdgcn_exp2f)
  return __builtin_amdgcn_exp2f(x);  // v_exp_f32: D = 2^x
#else
  return exp2f(x);
#endif
}

// ---------------- fused: input_proj -> GRU scan -> MHA ----------------
// grid: B * (F/8) = 512 blocks, 256 threads = 4 waves.
__global__ __launch_bounds__(256) void k_fused(
    const float* __restrict__ x, const float* __restrict__ Wp, const float* __restrict__ bp,
    const float* __restrict__ W_ih, const float* __restrict__ b_ih,
    const float* __restrict__ W_hh, const float* __restrict__ b_hh,
    const float* __restrict__ in_w, const float* __restrict__ in_b,
    const float* __restrict__ ow, const float* __restrict__ ob,
    float* __restrict__ outp, float* __restrict__ attn) {
  __shared__ float smem[SMEM_FLOATS];
  const int tid = threadIdx.x;
  const int blk = blockIdx.x;
  const int b = blk >> 4;
  const int f0 = (blk & 15) * 8;
  const int lane = tid & 63;
  const int w = tid >> 6;

  // ---- phase A: stage x[b] (64x128) into LDS; compute xp for this block's 8 f's ----
  {
    const float2* xb = (const float2*)(x + b * Tt * Ff);
    for (int i = tid; i < Tt * Ff / 2; i += 256) {
      int row = i >> 6, col2 = i & 63;
      *(float2*)&smem[row * XS_STRIDE + col2 * 2] = xb[i];
    }
  }
  __syncthreads();
  {
    const int t = lane;
    const int fA = f0 + w, fB = f0 + w + 4;      // wave-uniform -> Wp rows are scalar loads
    float acc0 = bp[fA], acc1 = bp[fB];
    const float* wA = Wp + fA * Ff;
    const float* wB = Wp + fB * Ff;
    const float* xr = &smem[t * XS_STRIDE];
#pragma unroll 8
    for (int k = 0; k < Ff; k += 2) {
      float2 xv = *(const float2*)&xr[k];
      acc0 = fmaf(xv.x, wA[k], acc0); acc0 = fmaf(xv.y, wA[k + 1], acc0);
      acc1 = fmaf(xv.x, wB[k], acc1); acc1 = fmaf(xv.y, wB[k + 1], acc1);
    }
    smem[XP_OFF + w * 65 + t] = acc0;            // xp_s[g=w][t]
    smem[XP_OFF + (w + 4) * 65 + t] = acc1;      // xp_s[g=w+4][t]
  }
  __syncthreads();   // xp_s ready; x-tile region reused below

  // ---- phase B: GRU scan over T, wave 0 only. lane = (g=f_local, j=hidden idx) ----
  // r/z gate rows pre-scaled by -log2e, n gate rows by +2*log2e so each gate is
  // {9 fma, exp2, add, rcp} with no division anywhere in the chain.
  if (tid < 64) {
    const int g = tid >> 3, j = tid & 7;
    const int f = f0 + g;
    const float* wb = W_hh + (f * G3H + j) * Hh;
    const float nL = -L2E, S2 = 2.0f * L2E;
    float w0s[8], w1s[8], w2s[8];
#pragma unroll
    for (int h = 0; h < 8; ++h) {
      w0s[h] = wb[h] * nL;         // gate r row j
      w1s[h] = wb[64 + h] * nL;    // gate z row 8+j
      w2s[h] = wb[128 + h] * S2;   // gate n row 16+j
    }
    const float wi0s = W_ih[f * G3H + j] * nL;
    const float wi1s = W_ih[f * G3H + 8 + j] * nL;
    const float wi2s = W_ih[f * G3H + 16 + j] * S2;
    const float bias_r = (b_ih[f * G3H + j] + b_hh[f * G3H + j]) * nL;
    const float bias_z = (b_ih[f * G3H + 8 + j] + b_hh[f * G3H + 8 + j]) * nL;
    const float bi2s = b_ih[f * G3H + 16 + j] * S2;
    const float bh2s = b_hh[f * G3H + 16 + j] * S2;
    float hall[8];
#pragma unroll
    for (int h = 0; h < 8; ++h) hall[h] = 0.f;
    const int base = tid & 56;
    float* hdst = &smem[HOUT_OFF + g * 520 + j * 65];
    const float* xps = &smem[XP_OFF + g * 65];
    for (int t = 0; t < Tt; ++t) {
      float xt = xps[t];
      float a0 = bias_r, a1 = bias_z, a2 = bh2s;
#pragma unroll
      for (int h = 0; h < 8; ++h) {
        a0 = fmaf(hall[h], w0s[h], a0);
        a1 = fmaf(hall[h], w1s[h], a1);
        a2 = fmaf(hall[h], w2s[h], a2);
      }
      float r = rcp_(1.0f + exp2_(fmaf(xt, wi0s, a0)));
      float z = rcp_(1.0f + exp2_(fmaf(xt, wi1s, a1)));
      float narg = fmaf(r, a2, fmaf(xt, wi2s, bi2s));
      float n = fmaf(-2.0f, rcp_(exp2_(narg) + 1.0f), 1.0f);   // tanh
      float hn = fmaf(z, hall[j] - n, n);                       // (1-z)*n + z*h
      hdst[t] = hn;
#pragma unroll
      for (int h = 0; h < 8; ++h) hall[h] = __shfl(hn, base + h, 64);
    }
  }
  __syncthreads();   // hout ready for all waves

  // ---- phase C: MHA per f; wave w handles f_local = w and w+4. lane = t ----
  {
    const int t = lane;
    float* kvw = &smem[KVS_OFF + w * 1024];
    for (int fl = w; fl < 8; fl += 4) {
      const int f = f0 + fl;
      const float* hsrc = &smem[HOUT_OFF + fl * 520];
      float sq[8];
#pragma unroll
      for (int h = 0; h < 8; ++h) sq[h] = hsrc[h * 65 + t];   // conflict-free
      // coalesced h -> global ws for out_proj kernel
      {
        float4* og = (float4*)(outp + ((b * Ff + f) * Tt + t) * Hh);
        float4 h0 = {sq[0], sq[1], sq[2], sq[3]};
        float4 h1 = {sq[4], sq[5], sq[6], sq[7]};
        og[0] = h0; og[1] = h1;
      }
      // qkv projection (in_w wave-uniform -> scalar loads)
      float q[8], ka[8], va[8];
#pragma unroll
      for (int jj = 0; jj < 8; ++jj) {
        float aq = in_b[jj], ak = in_b[8 + jj], av = in_b[16 + jj];
#pragma unroll
        for (int h = 0; h < 8; ++h) {
          aq = fmaf(sq[h], in_w[jj * 8 + h], aq);
          ak = fmaf(sq[h], in_w[(8 + jj) * 8 + h], ak);
          av = fmaf(sq[h], in_w[(16 + jj) * 8 + h], av);
        }
        q[jj] = aq; ka[jj] = ak; va[jj] = av;
      }
      // pack per-head (k0,k1,v0,v1) for uniform-broadcast b128 reads
#pragma unroll
      for (int n = 0; n < 4; ++n) {
        float4 kv = {ka[2 * n], ka[2 * n + 1], va[2 * n], va[2 * n + 1]};
        *(float4*)&kvw[t * 16 + n * 4] = kv;
      }
      asm volatile("s_waitcnt lgkmcnt(0)" ::: "memory");  // within-wave cross-lane LDS RAW
      // un-maxed softmax + PV; p = 2^(q.k * scale * log2e) == exp(q.k*scale)
      constexpr float SCL = 0.70710678118654752f * L2E;
      float ctx[8];
#pragma unroll
      for (int n = 0; n < 4; ++n) {
        float qs0 = q[2 * n] * SCL, qs1 = q[2 * n + 1] * SCL;
        float psum = 0.f, c0 = 0.f, c1 = 0.f;
        for (int kt = 0; kt < Tt; ++kt) {
          float4 kv = *(const float4*)&kvw[kt * 16 + n * 4];  // uniform addr -> broadcast
          float s = fmaf(qs0, kv.x, qs1 * kv.y);
          float p = exp2_(s);
          psum += p;
          c0 = fmaf(p, kv.z, c0);
          c1 = fmaf(p, kv.w, c1);
        }
        float inv = rcp_(psum);
        ctx[2 * n] = c0 * inv;
        ctx[2 * n + 1] = c1 * inv;
      }
      // out_proj of attention + store
      float o8[8];
#pragma unroll
      for (int jj = 0; jj < 8; ++jj) {
        float a = ob[jj];
#pragma unroll
        for (int h = 0; h < 8; ++h) a = fmaf(ctx[h], ow[jj * 8 + h], a);
        o8[jj] = a;
      }
      float4* dst = (float4*)(attn + ((b * Tt + t) * Ff + f) * Hh);
      float4 o0 = {o8[0], o8[1], o8[2], o8[3]};
      float4 o1 = {o8[4], o8[5], o8[6], o8[7]};
      dst[0] = o0; dst[1] = o1;
    }
  }
}

// ---------------- K4: y[b,t,o] = out[b,t,:,:] . Wout[o,:] + bout[o] ----------------
// grid: B*(T/4) = 512 blocks, 128 threads = 8 o-quads x 16 f-chunks. TT=4.
__global__ __launch_bounds__(128) void k_outproj(
    const float* __restrict__ outp, const float* __restrict__ Wout,
    const float* __restrict__ bout, float* __restrict__ y) {
  constexpr int TT = 4;
  int blk = blockIdx.x;
  int b = blk >> 4;
  int t0 = (blk & 15) * TT;
  int tid = threadIdx.x;
  int oq = tid >> 4;  // o in [oq*4, oq*4+4)
  int fc = tid & 15;  // f in [fc*8, fc*8+8)
  float acc[TT][4];
#pragma unroll
  for (int tt = 0; tt < TT; ++tt)
#pragma unroll
    for (int od = 0; od < 4; ++od) acc[tt][od] = 0.f;
#pragma unroll
  for (int ff = 0; ff < 8; ++ff) {
    int f = fc * 8 + ff;
    const float4* rb = (const float4*)(outp + ((b * Ff + f) * Tt + t0) * Hh);
    float4 rv[2 * TT];
#pragma unroll
    for (int i = 0; i < 2 * TT; ++i) rv[i] = rb[i];
#pragma unroll
    for (int od = 0; od < 4; ++od) {
      int o = oq * 4 + od;
      const float4* wbp = (const float4*)(Wout + o * (Ff * Hh) + f * Hh);
      float4 wa = wbp[0], wc = wbp[1];
#pragma unroll
      for (int tt = 0; tt < TT; ++tt) {
        float4 ra = rv[tt * 2], rc = rv[tt * 2 + 1];
        float s = acc[tt][od];
        s = fmaf(ra.x, wa.x, s); s = fmaf(ra.y, wa.y, s);
        s = fmaf(ra.z, wa.z, s); s = fmaf(ra.w, wa.w, s);
        s = fmaf(rc.x, wc.x, s); s = fmaf(rc.y, wc.y, s);
        s = fmaf(rc.z, wc.z, s); s = fmaf(rc.w, wc.w, s);
        acc[tt][od] = s;
      }
    }
  }
#pragma unroll
  for (int tt = 0; tt < TT; ++tt)
#pragma unroll
    for (int od = 0; od < 4; ++od) {
      float v = acc[tt][od];
      v += __shfl_xor(v, 1, 16);
      v += __shfl_xor(v, 2, 16);
      v += __shfl_xor(v, 4, 16);
      v += __shfl_xor(v, 8, 16);
      acc[tt][od] = v;
    }
#pragma unroll
  for (int tt = 0; tt < TT; ++tt) {
    if (fc == tt) {
#pragma unroll
      for (int od = 0; od < 4; ++od) {
        int o = oq * 4 + od;
        y[(b * Tt + t0 + tt) * HIDh + o] = acc[tt][od] + bout[o];
      }
    }
  }
}

extern "C" void kernel_launch(void* const* d_in, const int* in_sizes, int n_in,
                              void* d_out, int out_size, void* d_ws, size_t ws_size,
                              hipStream_t stream) {
  (void)in_sizes; (void)n_in; (void)out_size; (void)ws_size;
  const float* x    = (const float*)d_in[0];
  const float* Wp   = (const float*)d_in[1];
  const float* bp   = (const float*)d_in[2];
  const float* W_ih = (const float*)d_in[3];
  const float* b_ih = (const float*)d_in[4];
  const float* W_hh = (const float*)d_in[5];
  const float* b_hh = (const float*)d_in[6];
  const float* in_w = (const float*)d_in[7];
  const float* in_b = (const float*)d_in[8];
  const float* ow   = (const float*)d_in[9];
  const float* ob   = (const float*)d_in[10];
  const float* Wout = (const float*)d_in[11];
  const float* bout = (const float*)d_in[12];

  float* y    = (float*)d_out;                   // B*T*HID
  float* attn = (float*)d_out + Bb * Tt * HIDh;  // B*T*F*H
  float* outp = (float*)d_ws;                    // B*F*T*H

  hipLaunchKernelGGL(k_fused, dim3(Bb * (Ff / 8)), dim3(256), 0, stream,
                     x, Wp, bp, W_ih, b_ih, W_hh, b_hh, in_w, in_b, ow, ob, outp, attn);
  hipLaunchKernelGGL(k_outproj, dim3(Bb * (Tt / 4)), dim3(128), 0, stream,
                     outp, Wout, bout, y);
}

// Round 4
// 64.310 us; speedup vs baseline: 1.1667x; 1.1003x over previous
//
#include <hip/hip_runtime.h>

// MHAGRU, 3 kernels: [input_proj+GRU] -> [MHA] -> [out_proj].
// B=32 T=64 F=128 H=8 NH=4 HD=2 HID=32. All f32.
// d_out = [ y (B*T*HID) | attention (B*T*F*H) ]
// d_ws  = [ out (B*F*T*H) ]  (8 MB, fully overwritten each call)
//
// R4: un-fuse MHA into its own 4096x64 kernel (16 waves/CU) with 4-q-rows-per-lane
// kv reuse (4x fewer LDS ops); GRU kernel retires waves 1-3 after input_proj and
// streams h to global; out_proj reverted to R2 shape.

namespace {
constexpr int Bb = 32, Tt = 64, Ff = 128, Hh = 8, HIDh = 32;
constexpr int G3H = 24;  // 3*H
constexpr int XS_STRIDE = 130;
constexpr int XP_OFF = Tt * XS_STRIDE;   // 8320
constexpr int SMEM_AB = XP_OFF + 8 * 65; // 8840 floats = 35.4 KB
constexpr float L2E = 1.44269504088896340736f;
}

__device__ __forceinline__ float rcp_(float x) {
#if __has_builtin(__builtin_amdgcn_rcpf)
  return __builtin_amdgcn_rcpf(x);
#else
  return 1.0f / x;
#endif
}
__device__ __forceinline__ float exp2_(float x) {
#if __has_builtin(__builtin_amdgcn_exp2f)
  return __builtin_amdgcn_exp2f(x);
#else
  return exp2f(x);
#endif
}

// ---------------- K_AB: input_proj + per-feature GRU ----------------
// grid: B*(F/8) = 512 blocks, 256 threads. Waves 1-3 retire after phase A.
__global__ __launch_bounds__(256) void k_gruproj(
    const float* __restrict__ x, const float* __restrict__ Wp, const float* __restrict__ bp,
    const float* __restrict__ W_ih, const float* __restrict__ b_ih,
    const float* __restrict__ W_hh, const float* __restrict__ b_hh,
    float* __restrict__ outp) {
  __shared__ float smem[SMEM_AB];
  const int tid = threadIdx.x;
  const int blk = blockIdx.x;
  const int b = blk >> 4;
  const int f0 = (blk & 15) * 8;
  const int lane = tid & 63;
  const int w = tid >> 6;

  // phase A: stage x[b] (64x128), compute xp for this block's 8 f's
  {
    const float2* xb = (const float2*)(x + b * Tt * Ff);
    for (int i = tid; i < Tt * Ff / 2; i += 256) {
      int row = i >> 6, col2 = i & 63;
      *(float2*)&smem[row * XS_STRIDE + col2 * 2] = xb[i];
    }
  }
  __syncthreads();
  {
    const int t = lane;
    const int fA = f0 + w, fB = f0 + w + 4;  // wave-uniform -> scalar Wp loads
    float acc0 = bp[fA], acc1 = bp[fB];
    const float* wA = Wp + fA * Ff;
    const float* wB = Wp + fB * Ff;
    const float* xr = &smem[t * XS_STRIDE];
#pragma unroll 8
    for (int k = 0; k < Ff; k += 2) {
      float2 xv = *(const float2*)&xr[k];
      acc0 = fmaf(xv.x, wA[k], acc0); acc0 = fmaf(xv.y, wA[k + 1], acc0);
      acc1 = fmaf(xv.x, wB[k], acc1); acc1 = fmaf(xv.y, wB[k + 1], acc1);
    }
    smem[XP_OFF + w * 65 + t] = acc0;
    smem[XP_OFF + (w + 4) * 65 + t] = acc1;
  }
  __syncthreads();
  if (tid >= 64) return;   // free 3/4 of the block's wave slots

  // phase B: GRU scan, lane = (g=f_local, j=hidden). exp2/rcp form (R3).
  {
    const int g = tid >> 3, j = tid & 7;
    const int f = f0 + g;
    const float* wb = W_hh + (f * G3H + j) * Hh;
    const float nL = -L2E, S2 = 2.0f * L2E;
    float w0s[8], w1s[8], w2s[8];
#pragma unroll
    for (int h = 0; h < 8; ++h) {
      w0s[h] = wb[h] * nL;
      w1s[h] = wb[64 + h] * nL;
      w2s[h] = wb[128 + h] * S2;
    }
    const float wi0s = W_ih[f * G3H + j] * nL;
    const float wi1s = W_ih[f * G3H + 8 + j] * nL;
    const float wi2s = W_ih[f * G3H + 16 + j] * S2;
    const float bias_r = (b_ih[f * G3H + j] + b_hh[f * G3H + j]) * nL;
    const float bias_z = (b_ih[f * G3H + 8 + j] + b_hh[f * G3H + 8 + j]) * nL;
    const float bi2s = b_ih[f * G3H + 16 + j] * S2;
    const float bh2s = b_hh[f * G3H + 16 + j] * S2;
    float hall[8];
#pragma unroll
    for (int h = 0; h < 8; ++h) hall[h] = 0.f;
    const int base = tid & 56;
    float* outb = outp + ((b * Ff + f) * Tt) * Hh + j;
    const float* xps = &smem[XP_OFF + g * 65];
    for (int t = 0; t < Tt; ++t) {
      float xt = xps[t];
      float a0 = bias_r, a1 = bias_z, a2 = bh2s;
#pragma unroll
      for (int h = 0; h < 8; ++h) {
        a0 = fmaf(hall[h], w0s[h], a0);
        a1 = fmaf(hall[h], w1s[h], a1);
        a2 = fmaf(hall[h], w2s[h], a2);
      }
      float r = rcp_(1.0f + exp2_(fmaf(xt, wi0s, a0)));
      float z = rcp_(1.0f + exp2_(fmaf(xt, wi1s, a1)));
      float narg = fmaf(r, a2, fmaf(xt, wi2s, bi2s));
      float n = fmaf(-2.0f, rcp_(exp2_(narg) + 1.0f), 1.0f);  // tanh
      float hn = fmaf(z, hall[j] - n, n);
      outb[t * Hh] = hn;   // fire-and-forget global store
#pragma unroll
      for (int h = 0; h < 8; ++h) hall[h] = __shfl(hn, base + h, 64);
    }
  }
}

// ---------------- K_MHA: one (b,f) per 64-thread block ----------------
// C1: lane=t computes qkv, stages k/v/q in LDS.
// C2: lane=(qq,n): 4 q-rows x 1 head; kv float2 reused across 4 rows.
// C3: ctx exchange via LDS; out_proj cols {2n,2n+1} for 4 rows.
__global__ __launch_bounds__(64) void k_mha(
    const float* __restrict__ outp, const float* __restrict__ in_w,
    const float* __restrict__ in_b, const float* __restrict__ ow,
    const float* __restrict__ ob, float* __restrict__ attn) {
  __shared__ float kvs[4 * 130];  // k, [n][2t], head stride 130 (banks 2n+2t)
  __shared__ float vvs[4 * 130];  // v, same layout
  __shared__ float qs[64 * 10];   // q*scale, [t][2n], row stride 10
  __shared__ float cs[64 * 10];   // ctx, same layout
  const int blk = blockIdx.x;     // b*F + f
  const int b = blk >> 7, f = blk & 127;
  const int t = threadIdx.x;

  // ---- C1 ----
  const float4* src = (const float4*)(outp + blk * (Tt * Hh));
  float4 r0 = src[t * 2], r1 = src[t * 2 + 1];
  float sq[8] = {r0.x, r0.y, r0.z, r0.w, r1.x, r1.y, r1.z, r1.w};
  constexpr float SCL = 0.70710678118654752f * L2E;  // 1/sqrt(2) * log2e
  float qv[8], ka[8], va[8];
#pragma unroll
  for (int jj = 0; jj < 8; ++jj) {
    float aq = in_b[jj], ak = in_b[8 + jj], av = in_b[16 + jj];
#pragma unroll
    for (int h = 0; h < 8; ++h) {
      aq = fmaf(sq[h], in_w[jj * 8 + h], aq);
      ak = fmaf(sq[h], in_w[(8 + jj) * 8 + h], ak);
      av = fmaf(sq[h], in_w[(16 + jj) * 8 + h], av);
    }
    qv[jj] = aq * SCL; ka[jj] = ak; va[jj] = av;
  }
#pragma unroll
  for (int n = 0; n < 4; ++n) {
    *(float2*)&qs[t * 10 + 2 * n] = make_float2(qv[2 * n], qv[2 * n + 1]);
    *(float2*)&kvs[n * 130 + 2 * t] = make_float2(ka[2 * n], ka[2 * n + 1]);
    *(float2*)&vvs[n * 130 + 2 * t] = make_float2(va[2 * n], va[2 * n + 1]);
  }
  __syncthreads();

  // ---- C2 ----
  const int n = t & 3, qq = t >> 2;
  float q0[4], q1[4];
#pragma unroll
  for (int i = 0; i < 4; ++i) {
    float2 qp = *(const float2*)&qs[(qq + 16 * i) * 10 + 2 * n];
    q0[i] = qp.x; q1[i] = qp.y;
  }
  float ps[4], c0[4], c1[4];
#pragma unroll
  for (int i = 0; i < 4; ++i) { ps[i] = 0.f; c0[i] = 0.f; c1[i] = 0.f; }
#pragma unroll 4
  for (int kt = 0; kt < Tt; ++kt) {
    float2 kf = *(const float2*)&kvs[n * 130 + 2 * kt];  // 4 distinct banks, bcast
    float2 vf = *(const float2*)&vvs[n * 130 + 2 * kt];
#pragma unroll
    for (int i = 0; i < 4; ++i) {
      float s = fmaf(q0[i], kf.x, q1[i] * kf.y);
      float p = exp2_(s);
      ps[i] += p;
      c0[i] = fmaf(p, vf.x, c0[i]);
      c1[i] = fmaf(p, vf.y, c1[i]);
    }
  }
#pragma unroll
  for (int i = 0; i < 4; ++i) {
    float inv = rcp_(ps[i]);
    *(float2*)&cs[(qq + 16 * i) * 10 + 2 * n] = make_float2(c0[i] * inv, c1[i] * inv);
  }
  __syncthreads();

  // ---- C3: out_proj cols {2n, 2n+1} for rows qq+16i ----
  const float4* owp = (const float4*)(ow + n * 16);  // rows 2n,2n+1 of ow[8][8]
  float4 wv0 = owp[0], wv1 = owp[1], wv2 = owp[2], wv3 = owp[3];
  const float ob0 = ob[2 * n], ob1 = ob[2 * n + 1];
#pragma unroll
  for (int i = 0; i < 4; ++i) {
    int row = qq + 16 * i;
    float2 cp0 = *(const float2*)&cs[row * 10 + 0];
    float2 cp1 = *(const float2*)&cs[row * 10 + 2];
    float2 cp2 = *(const float2*)&cs[row * 10 + 4];
    float2 cp3 = *(const float2*)&cs[row * 10 + 6];
    float o0 = ob0, o1 = ob1;
    o0 = fmaf(cp0.x, wv0.x, o0); o0 = fmaf(cp0.y, wv0.y, o0);
    o0 = fmaf(cp1.x, wv0.z, o0); o0 = fmaf(cp1.y, wv0.w, o0);
    o0 = fmaf(cp2.x, wv1.x, o0); o0 = fmaf(cp2.y, wv1.y, o0);
    o0 = fmaf(cp3.x, wv1.z, o0); o0 = fmaf(cp3.y, wv1.w, o0);
    o1 = fmaf(cp0.x, wv2.x, o1); o1 = fmaf(cp0.y, wv2.y, o1);
    o1 = fmaf(cp1.x, wv2.z, o1); o1 = fmaf(cp1.y, wv2.w, o1);
    o1 = fmaf(cp2.x, wv3.x, o1); o1 = fmaf(cp2.y, wv3.y, o1);
    o1 = fmaf(cp3.x, wv3.z, o1); o1 = fmaf(cp3.y, wv3.w, o1);
    *(float2*)&attn[((b * Tt + row) * Ff + f) * Hh + 2 * n] = make_float2(o0, o1);
  }
}

// ---------------- K4: y = out . Wout^T + bout (R2 config: TT=8, 256 blocks) ----
__global__ __launch_bounds__(128) void k_outproj(
    const float* __restrict__ outp, const float* __restrict__ Wout,
    const float* __restrict__ bout, float* __restrict__ y) {
  constexpr int TT = 8;
  int blk = blockIdx.x;
  int b = blk >> 3;
  int t0 = (blk & 7) * TT;
  int tid = threadIdx.x;
  int oq = tid >> 4;
  int fc = tid & 15;
  float acc[TT][4];
#pragma unroll
  for (int tt = 0; tt < TT; ++tt)
#pragma unroll
    for (int od = 0; od < 4; ++od) acc[tt][od] = 0.f;
#pragma unroll
  for (int ff = 0; ff < 8; ++ff) {
    int f = fc * 8 + ff;
    const float4* rb = (const float4*)(outp + ((b * Ff + f) * Tt + t0) * Hh);
    float4 rv[16];
#pragma unroll
    for (int i = 0; i < 16; ++i) rv[i] = rb[i];
#pragma unroll
    for (int od = 0; od < 4; ++od) {
      int o = oq * 4 + od;
      const float4* wbp = (const float4*)(Wout + o * (Ff * Hh) + f * Hh);
      float4 wa = wbp[0], wc = wbp[1];
#pragma unroll
      for (int tt = 0; tt < TT; ++tt) {
        float4 ra = rv[tt * 2], rc = rv[tt * 2 + 1];
        float s = acc[tt][od];
        s = fmaf(ra.x, wa.x, s); s = fmaf(ra.y, wa.y, s);
        s = fmaf(ra.z, wa.z, s); s = fmaf(ra.w, wa.w, s);
        s = fmaf(rc.x, wc.x, s); s = fmaf(rc.y, wc.y, s);
        s = fmaf(rc.z, wc.z, s); s = fmaf(rc.w, wc.w, s);
        acc[tt][od] = s;
      }
    }
  }
#pragma unroll
  for (int tt = 0; tt < TT; ++tt)
#pragma unroll
    for (int od = 0; od < 4; ++od) {
      float v = acc[tt][od];
      v += __shfl_xor(v, 1, 16);
      v += __shfl_xor(v, 2, 16);
      v += __shfl_xor(v, 4, 16);
      v += __shfl_xor(v, 8, 16);
      acc[tt][od] = v;
    }
#pragma unroll
  for (int tt = 0; tt < TT; ++tt) {
    if (fc == tt) {
#pragma unroll
      for (int od = 0; od < 4; ++od) {
        int o = oq * 4 + od;
        y[(b * Tt + t0 + tt) * HIDh + o] = acc[tt][od] + bout[o];
      }
    }
  }
}

extern "C" void kernel_launch(void* const* d_in, const int* in_sizes, int n_in,
                              void* d_out, int out_size, void* d_ws, size_t ws_size,
                              hipStream_t stream) {
  (void)in_sizes; (void)n_in; (void)out_size; (void)ws_size;
  const float* x    = (const float*)d_in[0];
  const float* Wp   = (const float*)d_in[1];
  const float* bp   = (const float*)d_in[2];
  const float* W_ih = (const float*)d_in[3];
  const float* b_ih = (const float*)d_in[4];
  const float* W_hh = (const float*)d_in[5];
  const float* b_hh = (const float*)d_in[6];
  const float* in_w = (const float*)d_in[7];
  const float* in_b = (const float*)d_in[8];
  const float* ow   = (const float*)d_in[9];
  const float* ob   = (const float*)d_in[10];
  const float* Wout = (const float*)d_in[11];
  const float* bout = (const float*)d_in[12];

  float* y    = (float*)d_out;
  float* attn = (float*)d_out + Bb * Tt * HIDh;
  float* outp = (float*)d_ws;   // B*F*T*H

  hipLaunchKernelGGL(k_gruproj, dim3(Bb * (Ff / 8)), dim3(256), 0, stream,
                     x, Wp, bp, W_ih, b_ih, W_hh, b_hh, outp);
  hipLaunchKernelGGL(k_mha, dim3(Bb * Ff), dim3(64), 0, stream,
                     outp, in_w, in_b, ow, ob, attn);
  hipLaunchKernelGGL(k_outproj, dim3(Bb * (Tt / 8)), dim3(128), 0, stream,
                     outp, Wout, bout, y);
}